// Round 6
// baseline (2477.083 us; speedup 1.0000x reference)
//
#include <hip/hip_runtime.h>
#include <hip/hip_bf16.h>
#include <math.h>

#define F 128
#define H 256
#define C 40
#define KHOPS 10
#define TM 64
#define HK 64

// ---------------- CSR build ----------------
__global__ void k_count(const int* __restrict__ dst, int E, int* __restrict__ cnt) {
    int e = blockIdx.x * 256 + threadIdx.x;
    if (e < E) atomicAdd(&cnt[dst[e]], 1);
}

__global__ void k_scan1(const int* __restrict__ cnt, int n, int* __restrict__ bsum) {
    __shared__ int sh[256];
    int t = threadIdx.x;
    int base = blockIdx.x * 4096 + t * 16;
    int s = 0;
    for (int i = 0; i < 16; i++) { int idx = base + i; if (idx < n) s += cnt[idx]; }
    sh[t] = s; __syncthreads();
    for (int o = 128; o > 0; o >>= 1) {
        if (t < o) sh[t] += sh[t + o];
        __syncthreads();
    }
    if (t == 0) bsum[blockIdx.x] = sh[0];
}

__global__ void k_scan2(int* __restrict__ bsum, int nb) {
    if (threadIdx.x == 0) {
        int acc = 0;
        for (int i = 0; i < nb; i++) { int v = bsum[i]; bsum[i] = acc; acc += v; }
    }
}

__global__ void k_scan3(const int* __restrict__ cnt, int n, const int* __restrict__ bsum,
                        int* __restrict__ rp) {
    __shared__ int sh[256];
    int t = threadIdx.x;
    int base = blockIdx.x * 4096 + t * 16;
    int local[16]; int s = 0;
    for (int i = 0; i < 16; i++) {
        int idx = base + i;
        int v = (idx < n) ? cnt[idx] : 0;
        local[i] = v; s += v;
    }
    sh[t] = s; __syncthreads();
    for (int o = 1; o < 256; o <<= 1) {
        int v = (t >= o) ? sh[t - o] : 0;
        __syncthreads();
        sh[t] += v;
        __syncthreads();
    }
    int excl = (t == 0) ? 0 : sh[t - 1];
    int run = bsum[blockIdx.x] + excl;
    for (int i = 0; i < 16; i++) {
        int idx = base + i;
        if (idx < n) { rp[idx] = run; run += local[i]; }
    }
}

__global__ void k_fill(const int* __restrict__ src, const int* __restrict__ dst,
                       const float* __restrict__ nrm, int E, const int* __restrict__ rp,
                       int* __restrict__ cur, int2* __restrict__ ep) {
    int e = blockIdx.x * 256 + threadIdx.x;
    if (e < E) {
        int d = dst[e];
        int p = rp[d] + atomicAdd(&cur[d], 1);
        ep[p] = make_int2(src[e], __float_as_int(nrm[e]));
    }
}

// ---- degree histogram / scan / scatter: perm = nodes sorted by in-degree ----
__global__ void k_hist(const int* __restrict__ deg, int N, int* __restrict__ hist) {
    int n = blockIdx.x * 256 + threadIdx.x;
    if (n < N) atomicAdd(&hist[min(deg[n], 1023)], 1);
}

__global__ void k_hscan(int* __restrict__ hist) {   // 1024 threads, exclusive scan
    __shared__ int sh[1024];
    int t = threadIdx.x;
    sh[t] = hist[t];
    __syncthreads();
    for (int o = 1; o < 1024; o <<= 1) {
        int v = (t >= o) ? sh[t - o] : 0;
        __syncthreads();
        sh[t] += v;
        __syncthreads();
    }
    hist[t] = (t == 0) ? 0 : sh[t - 1];
}

__global__ void k_perm(const int* __restrict__ deg, int N, int* __restrict__ hoff,
                       int* __restrict__ perm) {
    int n = blockIdx.x * 256 + threadIdx.x;
    if (n < N) {
        int b = min(deg[n], 1023);
        int p = atomicAdd(&hoff[b], 1);
        perm[p] = n;
    }
}

// ---------------- W2 transpose: [H][C] -> [C][H] (kept for possible reuse) --------
__global__ void k_wt(const float* __restrict__ W2, float* __restrict__ w2t) {
    int t = blockIdx.x * 256 + threadIdx.x;
    if (t < H * C) { int h = t / C, c = t % C; w2t[c * H + h] = W2[t]; }
}

// ------- fused MLP: Linear(128->256)+BN+ReLU+Linear(256->40) + snapshot-0 combine -------
__launch_bounds__(256, 2)
__global__ void k_mlp(const float* __restrict__ x, const float* __restrict__ W1,
                      const float* __restrict__ b1, const float* __restrict__ g,
                      const float* __restrict__ be, const float* __restrict__ mu,
                      const float* __restrict__ var, const float* __restrict__ W2,
                      const float* __restrict__ b2, const float* __restrict__ pw,
                      const float* __restrict__ pb,
                      float* __restrict__ hbuf, int cp, float* __restrict__ oacc, int N) {
    __shared__ float xs[TM][132];   // [node][f]; rows tn+16i share bank offset -> 2-way max
    __shared__ float h1s[TM][68];   // [node][hh]; reused as epilogue scratch
    __shared__ float w2s[C][68];    // [c][hh] transposed
    __shared__ float asc[HK], dsc[HK];
    __shared__ float redc[256];
    __shared__ float sigv[TM];

    int t = threadIdx.x;
    int n0 = blockIdx.x * TM;

    // stage x tile (coalesced global, natural LDS layout)
    for (int k = 0; k < 8; k++) {
        int idx = k * 256 + t;          // over 2048 float4
        int node = idx >> 5, f4 = idx & 31;
        int n = n0 + node;
        float4 v = (n < N) ? ((const float4*)x)[(size_t)n * (F / 4) + f4]
                           : make_float4(0.f, 0.f, 0.f, 0.f);
        *((float4*)&xs[node][f4 * 4]) = v;
    }

    float acc2[10];
    {
        int cg = t & 3;
        #pragma unroll
        for (int j = 0; j < 10; j++) acc2[j] = b2[cg * 10 + j];
    }

    int tn = t & 15, th = t >> 4;
    const float4* W1g = (const float4*)W1;   // [F][H/4]

    for (int h0 = 0; h0 < H; h0 += HK) {
        // load W2 chunk transposed
        for (int k = 0; k < 10; k++) {
            int idx = k * 256 + t;      // over 2560
            int hh = idx / 40, c = idx % 40;
            w2s[c][hh] = W2[(size_t)(h0 + hh) * C + c];
        }
        // fused BN scale/shift (includes b1)
        if (t < HK) {
            int hg = h0 + t;
            float a = g[hg] * rsqrtf(var[hg] + 1e-5f);
            asc[t] = a;
            dsc[t] = (b1[hg] - mu[hg]) * a + be[hg];
        }
        __syncthreads();

        // stage 1: x @ W1 chunk (W1 from global: 16-lane broadcast b128, L2-hot)
        float acc[4][4];
        #pragma unroll
        for (int i = 0; i < 4; i++)
            #pragma unroll
            for (int j = 0; j < 4; j++) acc[i][j] = 0.f;

        #pragma unroll 4
        for (int f0 = 0; f0 < F; f0 += 4) {
            float4 wv[4];
            #pragma unroll
            for (int q = 0; q < 4; q++)
                wv[q] = W1g[(size_t)(f0 + q) * (H / 4) + (h0 >> 2) + th];
            float4 xv[4];
            #pragma unroll
            for (int i = 0; i < 4; i++)
                xv[i] = *((const float4*)&xs[tn + 16 * i][f0]);
            #pragma unroll
            for (int i = 0; i < 4; i++) {
                float xa[4] = {xv[i].x, xv[i].y, xv[i].z, xv[i].w};
                #pragma unroll
                for (int q = 0; q < 4; q++) {
                    float wa[4] = {wv[q].x, wv[q].y, wv[q].z, wv[q].w};
                    #pragma unroll
                    for (int j = 0; j < 4; j++) acc[i][j] += xa[q] * wa[j];
                }
            }
        }
        // BN + ReLU -> h1s
        #pragma unroll
        for (int i = 0; i < 4; i++) {
            float4 o;
            float* po = (float*)&o;
            #pragma unroll
            for (int j = 0; j < 4; j++) {
                int hh = th * 4 + j;
                float v = acc[i][j] * asc[hh] + dsc[hh];
                po[j] = v > 0.f ? v : 0.f;
            }
            *((float4*)&h1s[tn + 16 * i][th * 4]) = o;
        }
        __syncthreads();

        // stage 2: h1 chunk @ W2 chunk (w2s LDS, broadcast within quads)
        int n_loc = t >> 2, cg = t & 3;
        #pragma unroll 4
        for (int hh = 0; hh < HK; hh += 4) {
            float4 hv = *((const float4*)&h1s[n_loc][hh]);
            #pragma unroll
            for (int j = 0; j < 10; j++) {
                float4 w4 = *((const float4*)&w2s[cg * 10 + j][hh]);
                acc2[j] += hv.x * w4.x + hv.y * w4.y + hv.z * w4.z + hv.w * w4.w;
            }
        }
        __syncthreads();
    }

    // epilogue: stash h into LDS, sigmoid per node, write padded h row + out init
    int n_loc = t >> 2, cg = t & 3;
    #pragma unroll
    for (int j = 0; j < 10; j++) h1s[n_loc][cg * 10 + j] = acc2[j];
    float part = 0.f;
    #pragma unroll
    for (int j = 0; j < 10; j++) part += acc2[j] * pw[cg * 10 + j];
    redc[t] = part;
    __syncthreads();
    if (cg == 0) {
        float s = redc[n_loc * 4] + redc[n_loc * 4 + 1] + redc[n_loc * 4 + 2] + redc[n_loc * 4 + 3];
        sigv[n_loc] = 1.f / (1.f + expf(-(s + pb[0])));
    }
    __syncthreads();
    for (int k = 0; k < 2; k++) {
        int idx = k * 256 + t;          // 320 pack tasks: 64 rows x 5 packs of 8 floats
        if (idx < 320) {
            int row = idx / 5, p = idx % 5;
            int n = n0 + row;
            if (n < N) {
                float4 a, b;
                a.x = h1s[row][8 * p + 0]; a.y = h1s[row][8 * p + 1];
                a.z = h1s[row][8 * p + 2]; a.w = h1s[row][8 * p + 3];
                b.x = h1s[row][8 * p + 4]; b.y = h1s[row][8 * p + 5];
                b.z = h1s[row][8 * p + 6]; b.w = h1s[row][8 * p + 7];
                float4* hp = (float4*)(hbuf + (size_t)n * cp + 8 * p);
                hp[0] = a; hp[1] = b;
                float sg = sigv[row];
                float4 oa, ob;
                oa.x = sg * a.x; oa.y = sg * a.y; oa.z = sg * a.z; oa.w = sg * a.w;
                ob.x = sg * b.x; ob.y = sg * b.y; ob.z = sg * b.z; ob.w = sg * b.w;
                float4* op = (float4*)(oacc + (size_t)n * C + 8 * p);
                op[0] = oa; op[1] = ob;
            }
        }
    }
}

// ---------------- one propagation hop, fused with retain-combine ----------------
// 320 threads: 64 degree-sorted nodes/block (via perm), 5 lanes/node, 2 float4/lane.
__global__ void k_hop(const float4* __restrict__ cur4, float4* __restrict__ nxt4,
                      float4* __restrict__ oacc4, const int* __restrict__ rp,
                      const int2* __restrict__ ep, const int* __restrict__ perm, int cp4,
                      const float* __restrict__ pw, const float* __restrict__ pb, int N) {
    __shared__ float red[320];
    __shared__ float sig[64];
    int t = threadIdx.x;
    int nl = t / 5, p = t % 5;
    int idx = blockIdx.x * 64 + nl;
    int n = (idx < N) ? perm[idx] : -1;
    int c0 = 2 * p;
    float4 a0 = make_float4(0.f, 0.f, 0.f, 0.f);
    float4 a1 = make_float4(0.f, 0.f, 0.f, 0.f);
    if (n >= 0) {
        int b = rp[n], e = rp[n + 1];
        int j = b;
        for (; j + 4 <= e; j += 4) {
            int2 e0 = ep[j], e1 = ep[j + 1], e2 = ep[j + 2], e3 = ep[j + 3];
            const float4* r0 = cur4 + (size_t)e0.x * cp4 + c0;
            const float4* r1 = cur4 + (size_t)e1.x * cp4 + c0;
            const float4* r2 = cur4 + (size_t)e2.x * cp4 + c0;
            const float4* r3 = cur4 + (size_t)e3.x * cp4 + c0;
            float4 v00 = r0[0], v01 = r0[1];
            float4 v10 = r1[0], v11 = r1[1];
            float4 v20 = r2[0], v21 = r2[1];
            float4 v30 = r3[0], v31 = r3[1];
            float w0 = __int_as_float(e0.y), w1 = __int_as_float(e1.y);
            float w2 = __int_as_float(e2.y), w3 = __int_as_float(e3.y);
            a0.x += w0 * v00.x; a0.y += w0 * v00.y; a0.z += w0 * v00.z; a0.w += w0 * v00.w;
            a1.x += w0 * v01.x; a1.y += w0 * v01.y; a1.z += w0 * v01.z; a1.w += w0 * v01.w;
            a0.x += w1 * v10.x; a0.y += w1 * v10.y; a0.z += w1 * v10.z; a0.w += w1 * v10.w;
            a1.x += w1 * v11.x; a1.y += w1 * v11.y; a1.z += w1 * v11.z; a1.w += w1 * v11.w;
            a0.x += w2 * v20.x; a0.y += w2 * v20.y; a0.z += w2 * v20.z; a0.w += w2 * v20.w;
            a1.x += w2 * v21.x; a1.y += w2 * v21.y; a1.z += w2 * v21.z; a1.w += w2 * v21.w;
            a0.x += w3 * v30.x; a0.y += w3 * v30.y; a0.z += w3 * v30.z; a0.w += w3 * v30.w;
            a1.x += w3 * v31.x; a1.y += w3 * v31.y; a1.z += w3 * v31.z; a1.w += w3 * v31.w;
        }
        if (j + 2 <= e) {
            int2 e0 = ep[j], e1 = ep[j + 1];
            const float4* r0 = cur4 + (size_t)e0.x * cp4 + c0;
            const float4* r1 = cur4 + (size_t)e1.x * cp4 + c0;
            float4 v00 = r0[0], v01 = r0[1];
            float4 v10 = r1[0], v11 = r1[1];
            float w0 = __int_as_float(e0.y), w1 = __int_as_float(e1.y);
            a0.x += w0 * v00.x; a0.y += w0 * v00.y; a0.z += w0 * v00.z; a0.w += w0 * v00.w;
            a1.x += w0 * v01.x; a1.y += w0 * v01.y; a1.z += w0 * v01.z; a1.w += w0 * v01.w;
            a0.x += w1 * v10.x; a0.y += w1 * v10.y; a0.z += w1 * v10.z; a0.w += w1 * v10.w;
            a1.x += w1 * v11.x; a1.y += w1 * v11.y; a1.z += w1 * v11.z; a1.w += w1 * v11.w;
            j += 2;
        }
        if (j < e) {
            int2 e0 = ep[j];
            const float4* r0 = cur4 + (size_t)e0.x * cp4 + c0;
            float4 v00 = r0[0], v01 = r0[1];
            float w0 = __int_as_float(e0.y);
            a0.x += w0 * v00.x; a0.y += w0 * v00.y; a0.z += w0 * v00.z; a0.w += w0 * v00.w;
            a1.x += w0 * v01.x; a1.y += w0 * v01.y; a1.z += w0 * v01.z; a1.w += w0 * v01.w;
        }
        nxt4[(size_t)n * cp4 + c0] = a0;
        nxt4[(size_t)n * cp4 + c0 + 1] = a1;
    }
    // retain-combine
    float4 pw0 = ((const float4*)pw)[c0];
    float4 pw1 = ((const float4*)pw)[c0 + 1];
    red[t] = a0.x * pw0.x + a0.y * pw0.y + a0.z * pw0.z + a0.w * pw0.w
           + a1.x * pw1.x + a1.y * pw1.y + a1.z * pw1.z + a1.w * pw1.w;
    __syncthreads();
    if (p == 0) {
        float s = red[t] + red[t + 1] + red[t + 2] + red[t + 3] + red[t + 4];
        sig[nl] = 1.f / (1.f + expf(-(s + pb[0])));
    }
    __syncthreads();
    if (n >= 0) {
        float sg = sig[nl];
        size_t o = (size_t)n * 10 + c0;      // oacc packed [N][40]
        float4 v0 = oacc4[o], v1 = oacc4[o + 1];
        v0.x += sg * a0.x; v0.y += sg * a0.y; v0.z += sg * a0.z; v0.w += sg * a0.w;
        v1.x += sg * a1.x; v1.y += sg * a1.y; v1.z += sg * a1.z; v1.w += sg * a1.w;
        oacc4[o] = v0;
        oacc4[o + 1] = v1;
    }
}

// ---------------- in-place log_softmax over C (float4) ----------------
__global__ void k_lsm(float4* __restrict__ io, int N) {
    __shared__ float red[320];
    __shared__ float statm[32];
    __shared__ float stats[32];
    int t = threadIdx.x;
    int nl = t / 10, c4 = t % 10;
    int n = blockIdx.x * 32 + nl;
    bool ok = n < N;
    float4 v = ok ? io[(size_t)n * 10 + c4] : make_float4(-1e30f, -1e30f, -1e30f, -1e30f);
    red[t] = fmaxf(fmaxf(v.x, v.y), fmaxf(v.z, v.w));
    __syncthreads();
    if (c4 == 0) {
        float m = -1e30f;
        #pragma unroll
        for (int q = 0; q < 10; q++) m = fmaxf(m, red[nl * 10 + q]);
        statm[nl] = m;
    }
    __syncthreads();
    float m = statm[nl];
    float e0 = expf(v.x - m), e1 = expf(v.y - m), e2 = expf(v.z - m), e3 = expf(v.w - m);
    red[t] = e0 + e1 + e2 + e3;
    __syncthreads();
    if (c4 == 0) {
        float s = 0.f;
        #pragma unroll
        for (int q = 0; q < 10; q++) s += red[nl * 10 + q];
        stats[nl] = logf(s);
    }
    __syncthreads();
    if (ok) {
        float ls = stats[nl];
        io[(size_t)n * 10 + c4] = make_float4(v.x - m - ls, v.y - m - ls, v.z - m - ls, v.w - m - ls);
    }
}

extern "C" void kernel_launch(void* const* d_in, const int* in_sizes, int n_in,
                              void* d_out, int out_size, void* d_ws, size_t ws_size,
                              hipStream_t stream) {
    const float* x   = (const float*)d_in[0];
    const int*   ei  = (const int*)d_in[1];     // [2,E]: src row then dst row
    const float* nrm = (const float*)d_in[2];
    const float* W1  = (const float*)d_in[3];
    const float* b1  = (const float*)d_in[4];
    const float* g   = (const float*)d_in[5];
    const float* be  = (const float*)d_in[6];
    const float* mu  = (const float*)d_in[7];
    const float* var = (const float*)d_in[8];
    const float* W2  = (const float*)d_in[9];
    const float* b2  = (const float*)d_in[10];
    const float* pw  = (const float*)d_in[11];
    const float* pb  = (const float*)d_in[12];
    float* out = (float*)d_out;

    int N = in_sizes[0] / F;
    int E = in_sizes[2];

    auto alup = [](size_t b) { return ((b + 255) / 256) * 256; };
    size_t fixedB = alup((size_t)(N + 1) * 4) * 2 + alup(1024) + alup(4096)
                  + alup((size_t)N * 4) + alup((size_t)E * 8);
    // padded rows (256 B): exactly 2 aligned cache lines per edge gather
    int cp = (ws_size >= fixedB + 2 * alup((size_t)N * 64 * 4)) ? 64 : 40;

    char* w = (char*)d_ws;
    auto alloc = [&](size_t bytes) {
        void* p = (void*)w;
        w += ((bytes + 255) / 256) * 256;
        return p;
    };
    int*   rp     = (int*)alloc((size_t)(N + 1) * 4);
    int*   cursor = (int*)alloc((size_t)(N + 1) * 4);
    int*   bsum   = (int*)alloc(1024);
    int*   hist   = (int*)alloc(4096);
    int*   perm   = (int*)alloc((size_t)N * 4);
    int2*  ep     = (int2*)alloc((size_t)E * 8);
    float* bufA   = (float*)alloc((size_t)N * cp * 4);
    float* bufB   = (float*)alloc((size_t)N * cp * 4);

    hipMemsetAsync(cursor, 0, (size_t)(N + 1) * 4, stream);
    hipMemsetAsync(hist, 0, 4096, stream);

    k_count<<<(E + 255) / 256, 256, 0, stream>>>(ei + E, E, cursor);

    int n1 = N + 1;
    int NB = (n1 + 4095) / 4096;
    k_scan1<<<NB, 256, 0, stream>>>(cursor, n1, bsum);
    k_scan2<<<1, 64, 0, stream>>>(bsum, NB);
    k_scan3<<<NB, 256, 0, stream>>>(cursor, n1, bsum, rp);

    hipMemsetAsync(cursor, 0, (size_t)(N + 1) * 4, stream);
    k_fill<<<(E + 255) / 256, 256, 0, stream>>>(ei, ei + E, nrm, E, rp, cursor, ep);
    // cursor[n] now == in-degree(n): counting-sort nodes by degree
    int NBn = (N + 255) / 256;
    k_hist<<<NBn, 256, 0, stream>>>(cursor, N, hist);
    k_hscan<<<1, 1024, 0, stream>>>(hist);
    k_perm<<<NBn, 256, 0, stream>>>(cursor, N, hist, perm);

    k_mlp<<<(N + TM - 1) / TM, 256, 0, stream>>>(x, W1, b1, g, be, mu, var, W2, b2,
                                                 pw, pb, bufA, cp, out, N);

    int nodeBlocks64 = (N + 63) / 64;
    float* cur = bufA;
    float* nxt = bufB;
    for (int k = 0; k < KHOPS; k++) {
        k_hop<<<nodeBlocks64, 320, 0, stream>>>((const float4*)cur, (float4*)nxt, (float4*)out,
                                                rp, ep, perm, cp / 4, pw, pb, N);
        float* tmp = cur; cur = nxt; nxt = tmp;
    }

    int nodeBlocks32 = (N + 31) / 32;
    k_lsm<<<nodeBlocks32, 320, 0, stream>>>((float4*)out, N);
}

// Round 7
// 1198.550 us; speedup vs baseline: 2.0667x; 2.0667x over previous
//
#include <hip/hip_runtime.h>
#include <hip/hip_bf16.h>
#include <math.h>

#define F 128
#define H 256
#define C 40
#define KHOPS 10
#define TM 32
#define HK 64

// ---------------- CSR build ----------------
__global__ void k_count(const int* __restrict__ dst, int E, int* __restrict__ cnt) {
    int e = blockIdx.x * 256 + threadIdx.x;
    if (e < E) atomicAdd(&cnt[dst[e]], 1);
}

__global__ void k_scan1(const int* __restrict__ cnt, int n, int* __restrict__ bsum) {
    __shared__ int sh[256];
    int t = threadIdx.x;
    int base = blockIdx.x * 4096 + t * 16;
    int s = 0;
    for (int i = 0; i < 16; i++) { int idx = base + i; if (idx < n) s += cnt[idx]; }
    sh[t] = s; __syncthreads();
    for (int o = 128; o > 0; o >>= 1) {
        if (t < o) sh[t] += sh[t + o];
        __syncthreads();
    }
    if (t == 0) bsum[blockIdx.x] = sh[0];
}

__global__ void k_scan2(int* __restrict__ bsum, int nb) {
    if (threadIdx.x == 0) {
        int acc = 0;
        for (int i = 0; i < nb; i++) { int v = bsum[i]; bsum[i] = acc; acc += v; }
    }
}

__global__ void k_scan3(const int* __restrict__ cnt, int n, const int* __restrict__ bsum,
                        int* __restrict__ rp) {
    __shared__ int sh[256];
    int t = threadIdx.x;
    int base = blockIdx.x * 4096 + t * 16;
    int local[16]; int s = 0;
    for (int i = 0; i < 16; i++) {
        int idx = base + i;
        int v = (idx < n) ? cnt[idx] : 0;
        local[i] = v; s += v;
    }
    sh[t] = s; __syncthreads();
    for (int o = 1; o < 256; o <<= 1) {
        int v = (t >= o) ? sh[t - o] : 0;
        __syncthreads();
        sh[t] += v;
        __syncthreads();
    }
    int excl = (t == 0) ? 0 : sh[t - 1];
    int run = bsum[blockIdx.x] + excl;
    for (int i = 0; i < 16; i++) {
        int idx = base + i;
        if (idx < n) { rp[idx] = run; run += local[i]; }
    }
}

__global__ void k_fill(const int* __restrict__ src, const int* __restrict__ dst,
                       const float* __restrict__ nrm, int E, const int* __restrict__ rp,
                       int* __restrict__ cur, int2* __restrict__ ep) {
    int e = blockIdx.x * 256 + threadIdx.x;
    if (e < E) {
        int d = dst[e];
        int p = rp[d] + atomicAdd(&cur[d], 1);
        ep[p] = make_int2(src[e], __float_as_int(nrm[e]));
    }
}

// ------- fused MLP: Linear(128->256)+BN+ReLU+Linear(256->40) + snapshot-0 combine -------
// TM=32 nodes/block: LDS ~38 KB -> 4 blocks/CU at __launch_bounds__(256,4), VGPR cap 128.
__launch_bounds__(256, 4)
__global__ void k_mlp(const float* __restrict__ x, const float* __restrict__ W1,
                      const float* __restrict__ b1, const float* __restrict__ g,
                      const float* __restrict__ be, const float* __restrict__ mu,
                      const float* __restrict__ var, const float* __restrict__ W2,
                      const float* __restrict__ b2, const float* __restrict__ pw,
                      const float* __restrict__ pb,
                      float* __restrict__ hbuf, float* __restrict__ oacc, int N) {
    __shared__ float xs[TM][132];   // 16.9 KB; rows tn+16i share bank offset -> 2-way max
    __shared__ float h1s[TM][68];   // 8.7 KB; reused as epilogue scratch
    __shared__ float w2s[C][68];    // 10.9 KB; [c][hh] transposed
    __shared__ float asc[HK], dsc[HK];
    __shared__ float redc[256];
    __shared__ float sigv[TM];

    int t = threadIdx.x;
    int n0 = blockIdx.x * TM;

    // stage x tile (coalesced global, natural LDS layout): 1024 float4
    for (int k = 0; k < 4; k++) {
        int idx = k * 256 + t;
        int node = idx >> 5, f4 = idx & 31;
        int n = n0 + node;
        float4 v = (n < N) ? ((const float4*)x)[(size_t)n * (F / 4) + f4]
                           : make_float4(0.f, 0.f, 0.f, 0.f);
        *((float4*)&xs[node][f4 * 4]) = v;
    }

    // stage 2 layout: 32 nodes x 8 channel-groups of 5
    int n_loc = t >> 3, cg = t & 7;
    float acc2[5];
    #pragma unroll
    for (int j = 0; j < 5; j++) acc2[j] = b2[cg * 5 + j];

    // stage-1 tiling: thread (tn,th): nodes {tn, tn+16} x hh quad th
    int tn = t & 15, th = t >> 4;
    const float4* W1g = (const float4*)W1;   // [F][H/4]

    for (int h0 = 0; h0 < H; h0 += HK) {
        // load W2 chunk transposed
        for (int k = 0; k < 10; k++) {
            int idx = k * 256 + t;      // over 2560
            int hh = idx / 40, c = idx % 40;
            w2s[c][hh] = W2[(size_t)(h0 + hh) * C + c];
        }
        // fused BN scale/shift (includes b1)
        if (t < HK) {
            int hg = h0 + t;
            float a = g[hg] * rsqrtf(var[hg] + 1e-5f);
            asc[t] = a;
            dsc[t] = (b1[hg] - mu[hg]) * a + be[hg];
        }
        __syncthreads();

        // stage 1: x @ W1 chunk (W1 from global: broadcast b128, L1/L2-hot)
        float acc[2][4];
        #pragma unroll
        for (int i = 0; i < 2; i++)
            #pragma unroll
            for (int j = 0; j < 4; j++) acc[i][j] = 0.f;

        #pragma unroll 4
        for (int f0 = 0; f0 < F; f0 += 4) {
            float4 wv[4];
            #pragma unroll
            for (int q = 0; q < 4; q++)
                wv[q] = W1g[(size_t)(f0 + q) * (H / 4) + (h0 >> 2) + th];
            float4 xv[2];
            #pragma unroll
            for (int i = 0; i < 2; i++)
                xv[i] = *((const float4*)&xs[tn + 16 * i][f0]);
            #pragma unroll
            for (int i = 0; i < 2; i++) {
                float xa[4] = {xv[i].x, xv[i].y, xv[i].z, xv[i].w};
                #pragma unroll
                for (int q = 0; q < 4; q++) {
                    float wa[4] = {wv[q].x, wv[q].y, wv[q].z, wv[q].w};
                    #pragma unroll
                    for (int j = 0; j < 4; j++) acc[i][j] += xa[q] * wa[j];
                }
            }
        }
        // BN + ReLU -> h1s
        #pragma unroll
        for (int i = 0; i < 2; i++) {
            float4 o;
            float* po = (float*)&o;
            #pragma unroll
            for (int j = 0; j < 4; j++) {
                int hh = th * 4 + j;
                float v = acc[i][j] * asc[hh] + dsc[hh];
                po[j] = v > 0.f ? v : 0.f;
            }
            *((float4*)&h1s[tn + 16 * i][th * 4]) = o;
        }
        __syncthreads();

        // stage 2: h1 chunk @ W2 chunk (w2s LDS; h1s row broadcast among 8 lanes)
        #pragma unroll 4
        for (int hh = 0; hh < HK; hh += 4) {
            float4 hv = *((const float4*)&h1s[n_loc][hh]);
            #pragma unroll
            for (int j = 0; j < 5; j++) {
                float4 w4 = *((const float4*)&w2s[cg * 5 + j][hh]);
                acc2[j] += hv.x * w4.x + hv.y * w4.y + hv.z * w4.z + hv.w * w4.w;
            }
        }
        __syncthreads();
    }

    // epilogue: stash h into LDS, sigmoid per node, write h row + out init
    #pragma unroll
    for (int j = 0; j < 5; j++) h1s[n_loc][cg * 5 + j] = acc2[j];
    float part = 0.f;
    #pragma unroll
    for (int j = 0; j < 5; j++) part += acc2[j] * pw[cg * 5 + j];
    redc[t] = part;
    __syncthreads();
    if (cg == 0) {
        float s = 0.f;
        #pragma unroll
        for (int q = 0; q < 8; q++) s += redc[n_loc * 8 + q];
        sigv[n_loc] = 1.f / (1.f + expf(-(s + pb[0])));
    }
    __syncthreads();
    if (t < 160) {                      // 32 rows x 5 packs of 8 floats
        int row = t / 5, p = t % 5;
        int n = n0 + row;
        if (n < N) {
            float4 a, b;
            a.x = h1s[row][8 * p + 0]; a.y = h1s[row][8 * p + 1];
            a.z = h1s[row][8 * p + 2]; a.w = h1s[row][8 * p + 3];
            b.x = h1s[row][8 * p + 4]; b.y = h1s[row][8 * p + 5];
            b.z = h1s[row][8 * p + 6]; b.w = h1s[row][8 * p + 7];
            float4* hp = (float4*)(hbuf + (size_t)n * C + 8 * p);
            hp[0] = a; hp[1] = b;
            float sg = sigv[row];
            float4 oa, ob;
            oa.x = sg * a.x; oa.y = sg * a.y; oa.z = sg * a.z; oa.w = sg * a.w;
            ob.x = sg * b.x; ob.y = sg * b.y; ob.z = sg * b.z; ob.w = sg * b.w;
            float4* op = (float4*)(oacc + (size_t)n * C + 8 * p);
            op[0] = oa; op[1] = ob;
        }
    }
}

// ---------------- one propagation hop, fused with retain-combine ----------------
// 320 threads: 64 nodes/block (natural order), 5 lanes/node, 2 float4 per lane.
__global__ void k_hop(const float4* __restrict__ cur4, float4* __restrict__ nxt4,
                      float4* __restrict__ oacc4, const int* __restrict__ rp,
                      const int2* __restrict__ ep,
                      const float* __restrict__ pw, const float* __restrict__ pb, int N) {
    __shared__ float red[320];
    __shared__ float sig[64];
    int t = threadIdx.x;
    int nl = t / 5, p = t % 5;
    int n = blockIdx.x * 64 + nl;
    int c0 = 2 * p;
    float4 a0 = make_float4(0.f, 0.f, 0.f, 0.f);
    float4 a1 = make_float4(0.f, 0.f, 0.f, 0.f);
    if (n < N) {
        int b = rp[n], e = rp[n + 1];
        int j = b;
        for (; j + 4 <= e; j += 4) {
            int2 e0 = ep[j], e1 = ep[j + 1], e2 = ep[j + 2], e3 = ep[j + 3];
            const float4* r0 = cur4 + (size_t)e0.x * 10 + c0;
            const float4* r1 = cur4 + (size_t)e1.x * 10 + c0;
            const float4* r2 = cur4 + (size_t)e2.x * 10 + c0;
            const float4* r3 = cur4 + (size_t)e3.x * 10 + c0;
            float4 v00 = r0[0], v01 = r0[1];
            float4 v10 = r1[0], v11 = r1[1];
            float4 v20 = r2[0], v21 = r2[1];
            float4 v30 = r3[0], v31 = r3[1];
            float w0 = __int_as_float(e0.y), w1 = __int_as_float(e1.y);
            float w2 = __int_as_float(e2.y), w3 = __int_as_float(e3.y);
            a0.x += w0 * v00.x; a0.y += w0 * v00.y; a0.z += w0 * v00.z; a0.w += w0 * v00.w;
            a1.x += w0 * v01.x; a1.y += w0 * v01.y; a1.z += w0 * v01.z; a1.w += w0 * v01.w;
            a0.x += w1 * v10.x; a0.y += w1 * v10.y; a0.z += w1 * v10.z; a0.w += w1 * v10.w;
            a1.x += w1 * v11.x; a1.y += w1 * v11.y; a1.z += w1 * v11.z; a1.w += w1 * v11.w;
            a0.x += w2 * v20.x; a0.y += w2 * v20.y; a0.z += w2 * v20.z; a0.w += w2 * v20.w;
            a1.x += w2 * v21.x; a1.y += w2 * v21.y; a1.z += w2 * v21.z; a1.w += w2 * v21.w;
            a0.x += w3 * v30.x; a0.y += w3 * v30.y; a0.z += w3 * v30.z; a0.w += w3 * v30.w;
            a1.x += w3 * v31.x; a1.y += w3 * v31.y; a1.z += w3 * v31.z; a1.w += w3 * v31.w;
        }
        if (j + 2 <= e) {
            int2 e0 = ep[j], e1 = ep[j + 1];
            const float4* r0 = cur4 + (size_t)e0.x * 10 + c0;
            const float4* r1 = cur4 + (size_t)e1.x * 10 + c0;
            float4 v00 = r0[0], v01 = r0[1];
            float4 v10 = r1[0], v11 = r1[1];
            float w0 = __int_as_float(e0.y), w1 = __int_as_float(e1.y);
            a0.x += w0 * v00.x; a0.y += w0 * v00.y; a0.z += w0 * v00.z; a0.w += w0 * v00.w;
            a1.x += w0 * v01.x; a1.y += w0 * v01.y; a1.z += w0 * v01.z; a1.w += w0 * v01.w;
            a0.x += w1 * v10.x; a0.y += w1 * v10.y; a0.z += w1 * v10.z; a0.w += w1 * v10.w;
            a1.x += w1 * v11.x; a1.y += w1 * v11.y; a1.z += w1 * v11.z; a1.w += w1 * v11.w;
            j += 2;
        }
        if (j < e) {
            int2 e0 = ep[j];
            const float4* r0 = cur4 + (size_t)e0.x * 10 + c0;
            float4 v00 = r0[0], v01 = r0[1];
            float w0 = __int_as_float(e0.y);
            a0.x += w0 * v00.x; a0.y += w0 * v00.y; a0.z += w0 * v00.z; a0.w += w0 * v00.w;
            a1.x += w0 * v01.x; a1.y += w0 * v01.y; a1.z += w0 * v01.z; a1.w += w0 * v01.w;
        }
        nxt4[(size_t)n * 10 + c0] = a0;
        nxt4[(size_t)n * 10 + c0 + 1] = a1;
    }
    // retain-combine
    float4 pw0 = ((const float4*)pw)[c0];
    float4 pw1 = ((const float4*)pw)[c0 + 1];
    red[t] = a0.x * pw0.x + a0.y * pw0.y + a0.z * pw0.z + a0.w * pw0.w
           + a1.x * pw1.x + a1.y * pw1.y + a1.z * pw1.z + a1.w * pw1.w;
    __syncthreads();
    if (p == 0) {
        float s = red[t] + red[t + 1] + red[t + 2] + red[t + 3] + red[t + 4];
        sig[nl] = 1.f / (1.f + expf(-(s + pb[0])));
    }
    __syncthreads();
    if (n < N) {
        float sg = sig[nl];
        size_t o = (size_t)n * 10 + c0;
        float4 v0 = oacc4[o], v1 = oacc4[o + 1];
        v0.x += sg * a0.x; v0.y += sg * a0.y; v0.z += sg * a0.z; v0.w += sg * a0.w;
        v1.x += sg * a1.x; v1.y += sg * a1.y; v1.z += sg * a1.z; v1.w += sg * a1.w;
        oacc4[o] = v0;
        oacc4[o + 1] = v1;
    }
}

// ---------------- in-place log_softmax over C (float4) ----------------
__global__ void k_lsm(float4* __restrict__ io, int N) {
    __shared__ float red[320];
    __shared__ float statm[32];
    __shared__ float stats[32];
    int t = threadIdx.x;
    int nl = t / 10, c4 = t % 10;
    int n = blockIdx.x * 32 + nl;
    bool ok = n < N;
    float4 v = ok ? io[(size_t)n * 10 + c4] : make_float4(-1e30f, -1e30f, -1e30f, -1e30f);
    red[t] = fmaxf(fmaxf(v.x, v.y), fmaxf(v.z, v.w));
    __syncthreads();
    if (c4 == 0) {
        float m = -1e30f;
        #pragma unroll
        for (int q = 0; q < 10; q++) m = fmaxf(m, red[nl * 10 + q]);
        statm[nl] = m;
    }
    __syncthreads();
    float m = statm[nl];
    float e0 = expf(v.x - m), e1 = expf(v.y - m), e2 = expf(v.z - m), e3 = expf(v.w - m);
    red[t] = e0 + e1 + e2 + e3;
    __syncthreads();
    if (c4 == 0) {
        float s = 0.f;
        #pragma unroll
        for (int q = 0; q < 10; q++) s += red[nl * 10 + q];
        stats[nl] = logf(s);
    }
    __syncthreads();
    if (ok) {
        float ls = stats[nl];
        io[(size_t)n * 10 + c4] = make_float4(v.x - m - ls, v.y - m - ls, v.z - m - ls, v.w - m - ls);
    }
}

extern "C" void kernel_launch(void* const* d_in, const int* in_sizes, int n_in,
                              void* d_out, int out_size, void* d_ws, size_t ws_size,
                              hipStream_t stream) {
    const float* x   = (const float*)d_in[0];
    const int*   ei  = (const int*)d_in[1];     // [2,E]: src row then dst row
    const float* nrm = (const float*)d_in[2];
    const float* W1  = (const float*)d_in[3];
    const float* b1  = (const float*)d_in[4];
    const float* g   = (const float*)d_in[5];
    const float* be  = (const float*)d_in[6];
    const float* mu  = (const float*)d_in[7];
    const float* var = (const float*)d_in[8];
    const float* W2  = (const float*)d_in[9];
    const float* b2  = (const float*)d_in[10];
    const float* pw  = (const float*)d_in[11];
    const float* pb  = (const float*)d_in[12];
    float* out = (float*)d_out;

    int N = in_sizes[0] / F;
    int E = in_sizes[2];

    char* w = (char*)d_ws;
    auto alloc = [&](size_t bytes) {
        void* p = (void*)w;
        w += ((bytes + 255) / 256) * 256;
        return p;
    };
    int*   rp     = (int*)alloc((size_t)(N + 1) * 4);
    int*   cursor = (int*)alloc((size_t)(N + 1) * 4);
    int*   bsum   = (int*)alloc(1024);
    int2*  ep     = (int2*)alloc((size_t)E * 8);
    float* bufA   = (float*)alloc((size_t)N * C * 4);
    float* bufB   = (float*)alloc((size_t)N * C * 4);

    hipMemsetAsync(cursor, 0, (size_t)(N + 1) * 4, stream);

    k_count<<<(E + 255) / 256, 256, 0, stream>>>(ei + E, E, cursor);

    int n1 = N + 1;
    int NB = (n1 + 4095) / 4096;
    k_scan1<<<NB, 256, 0, stream>>>(cursor, n1, bsum);
    k_scan2<<<1, 64, 0, stream>>>(bsum, NB);
    k_scan3<<<NB, 256, 0, stream>>>(cursor, n1, bsum, rp);

    hipMemsetAsync(cursor, 0, (size_t)(N + 1) * 4, stream);
    k_fill<<<(E + 255) / 256, 256, 0, stream>>>(ei, ei + E, nrm, E, rp, cursor, ep);

    k_mlp<<<(N + TM - 1) / TM, 256, 0, stream>>>(x, W1, b1, g, be, mu, var, W2, b2,
                                                 pw, pb, bufA, out, N);

    int nodeBlocks64 = (N + 63) / 64;
    float* cur = bufA;
    float* nxt = bufB;
    for (int k = 0; k < KHOPS; k++) {
        k_hop<<<nodeBlocks64, 320, 0, stream>>>((const float4*)cur, (float4*)nxt, (float4*)out,
                                                rp, ep, pw, pb, N);
        float* tmp = cur; cur = nxt; nxt = tmp;
    }

    int nodeBlocks32 = (N + 31) / 32;
    k_lsm<<<nodeBlocks32, 320, 0, stream>>>((float4*)out, N);
}

// Round 8
// 1050.208 us; speedup vs baseline: 2.3587x; 1.1413x over previous
//
#include <hip/hip_runtime.h>
#include <hip/hip_bf16.h>
#include <math.h>

#define F 128
#define H 256
#define C 40
#define KHOPS 10
#define TM 32

typedef short bf16x8 __attribute__((ext_vector_type(8)));
typedef float f32x4 __attribute__((ext_vector_type(4)));

// exact 3-way bf16 split: v = f1 + f2 + f3 + O(2^-26 v); subtractions exact
__device__ __forceinline__ void split3(float v, ushort& s1, ushort& s2, ushort& s3) {
    unsigned u = __float_as_uint(v);
    float f1 = __uint_as_float(u & 0xFFFF0000u);
    s1 = (ushort)(u >> 16);
    float r = v - f1;
    unsigned ur = __float_as_uint(r);
    float f2 = __uint_as_float(ur & 0xFFFF0000u);
    s2 = (ushort)(ur >> 16);
    float r2 = r - f2;
    s3 = (ushort)(__float_as_uint(r2) >> 16);
}

// ---------------- CSR build ----------------
__global__ void k_count(const int* __restrict__ dst, int E, int* __restrict__ cnt) {
    int e = blockIdx.x * 256 + threadIdx.x;
    if (e < E) atomicAdd(&cnt[dst[e]], 1);
}

__global__ void k_scan1(const int* __restrict__ cnt, int n, int* __restrict__ bsum) {
    __shared__ int sh[256];
    int t = threadIdx.x;
    int base = blockIdx.x * 4096 + t * 16;
    int s = 0;
    for (int i = 0; i < 16; i++) { int idx = base + i; if (idx < n) s += cnt[idx]; }
    sh[t] = s; __syncthreads();
    for (int o = 128; o > 0; o >>= 1) {
        if (t < o) sh[t] += sh[t + o];
        __syncthreads();
    }
    if (t == 0) bsum[blockIdx.x] = sh[0];
}

__global__ void k_scan2(int* __restrict__ bsum, int nb) {
    if (threadIdx.x == 0) {
        int acc = 0;
        for (int i = 0; i < nb; i++) { int v = bsum[i]; bsum[i] = acc; acc += v; }
    }
}

__global__ void k_scan3(const int* __restrict__ cnt, int n, const int* __restrict__ bsum,
                        int* __restrict__ rp) {
    __shared__ int sh[256];
    int t = threadIdx.x;
    int base = blockIdx.x * 4096 + t * 16;
    int local[16]; int s = 0;
    for (int i = 0; i < 16; i++) {
        int idx = base + i;
        int v = (idx < n) ? cnt[idx] : 0;
        local[i] = v; s += v;
    }
    sh[t] = s; __syncthreads();
    for (int o = 1; o < 256; o <<= 1) {
        int v = (t >= o) ? sh[t - o] : 0;
        __syncthreads();
        sh[t] += v;
        __syncthreads();
    }
    int excl = (t == 0) ? 0 : sh[t - 1];
    int run = bsum[blockIdx.x] + excl;
    for (int i = 0; i < 16; i++) {
        int idx = base + i;
        if (idx < n) { rp[idx] = run; run += local[i]; }
    }
}

__global__ void k_fill(const int* __restrict__ src, const int* __restrict__ dst,
                       const float* __restrict__ nrm, int E, const int* __restrict__ rp,
                       int* __restrict__ cur, int2* __restrict__ ep) {
    int e = blockIdx.x * 256 + threadIdx.x;
    if (e < E) {
        int d = dst[e];
        int p = rp[d] + atomicAdd(&cur[d], 1);
        ep[p] = make_int2(src[e], __float_as_int(nrm[e]));
    }
}

// ---- W1 split to 3 bf16 arrays in B-fragment layout [h][f] (W1^T) ----
__global__ void k_wsplit(const float* __restrict__ W1, ushort* __restrict__ w1a,
                         ushort* __restrict__ w1b, ushort* __restrict__ w1c) {
    int t = blockIdx.x * 256 + threadIdx.x;
    if (t < F * H) {
        int h = t / F, f = t % F;
        ushort a, b, c;
        split3(W1[(size_t)f * H + h], a, b, c);
        w1a[t] = a; w1b[t] = b; w1c[t] = c;
    }
}

// ------- fused MLP: MFMA split-bf16 Linear(128->256) + BN+ReLU + VALU Linear(256->40)
//         + snapshot-0 retain-combine -------
__launch_bounds__(256)
__global__ void k_mlp(const float* __restrict__ x,
                      const ushort* __restrict__ w1a, const ushort* __restrict__ w1b,
                      const ushort* __restrict__ w1c,
                      const float* __restrict__ b1, const float* __restrict__ g,
                      const float* __restrict__ be, const float* __restrict__ mu,
                      const float* __restrict__ var, const float* __restrict__ W2,
                      const float* __restrict__ b2, const float* __restrict__ pw,
                      const float* __restrict__ pb,
                      float* __restrict__ hbuf, float* __restrict__ oacc, int N) {
    __shared__ ushort xsA[TM][136];   // x split hi   (pad 136: 2-way max)
    __shared__ ushort xsB[TM][136];   // x split mid
    __shared__ ushort xsC[TM][136];   // x split lo
    __shared__ float h1s[TM][260];    // fp32 h1; stride 260 -> conflict-free b128
    __shared__ float w2s[C][68];
    __shared__ float ascS[H], dscS[H];
    __shared__ float redc[256];
    __shared__ float sigv[TM];

    int t = threadIdx.x;
    int n0 = blockIdx.x * TM;

    // stage x tile, on-the-fly 3-way bf16 split into LDS
    for (int kk = 0; kk < 4; kk++) {
        int idx = kk * 256 + t;             // 1024 float4 = 32 nodes x 32 f4
        int node = idx >> 5, f4 = idx & 31;
        int n = n0 + node;
        float4 v = (n < N) ? ((const float4*)x)[(size_t)n * (F / 4) + f4]
                           : make_float4(0.f, 0.f, 0.f, 0.f);
        ushort4 pa, pm, pc;
        split3(v.x, pa.x, pm.x, pc.x);
        split3(v.y, pa.y, pm.y, pc.y);
        split3(v.z, pa.z, pm.z, pc.z);
        split3(v.w, pa.w, pm.w, pc.w);
        *((ushort4*)&xsA[node][f4 * 4]) = pa;
        *((ushort4*)&xsB[node][f4 * 4]) = pm;
        *((ushort4*)&xsC[node][f4 * 4]) = pc;
    }
    // BN coefficients (t == h, exactly 256 threads)
    {
        float a = g[t] * rsqrtf(var[t] + 1e-5f);
        ascS[t] = a;
        dscS[t] = (b1[t] - mu[t]) * a + be[t];
    }
    __syncthreads();

    // ---- stage 1: x @ W1 via MFMA, 6-term split product ----
    int lane = t & 63, wv = t >> 6, quad = lane >> 4, lq = lane & 15;
    int n0w = wv * 64;                      // this wave's H-chunk
    f32x4 acc[2][4];
    #pragma unroll
    for (int mi = 0; mi < 2; mi++)
        #pragma unroll
        for (int ni = 0; ni < 4; ni++)
            acc[mi][ni] = (f32x4){0.f, 0.f, 0.f, 0.f};

    #pragma unroll
    for (int ks = 0; ks < 4; ks++) {
        int k0 = ks * 32 + quad * 8;
        bf16x8 a1[2], a2[2], a3[2];
        #pragma unroll
        for (int mi = 0; mi < 2; mi++) {
            int row = mi * 16 + lq;         // A: m = lane&15
            a1[mi] = *((const bf16x8*)&xsA[row][k0]);
            a2[mi] = *((const bf16x8*)&xsB[row][k0]);
            a3[mi] = *((const bf16x8*)&xsC[row][k0]);
        }
        #pragma unroll
        for (int ni = 0; ni < 4; ni++) {
            size_t wo = (size_t)(n0w + ni * 16 + lq) * F + k0;   // B: n = lane&15, k contig
            bf16x8 q1 = *((const bf16x8*)(w1a + wo));
            bf16x8 q2 = *((const bf16x8*)(w1b + wo));
            bf16x8 q3 = *((const bf16x8*)(w1c + wo));
            #pragma unroll
            for (int mi = 0; mi < 2; mi++) {
                acc[mi][ni] = __builtin_amdgcn_mfma_f32_16x16x32_bf16(a1[mi], q1, acc[mi][ni], 0, 0, 0);
                acc[mi][ni] = __builtin_amdgcn_mfma_f32_16x16x32_bf16(a1[mi], q2, acc[mi][ni], 0, 0, 0);
                acc[mi][ni] = __builtin_amdgcn_mfma_f32_16x16x32_bf16(a2[mi], q1, acc[mi][ni], 0, 0, 0);
                acc[mi][ni] = __builtin_amdgcn_mfma_f32_16x16x32_bf16(a1[mi], q3, acc[mi][ni], 0, 0, 0);
                acc[mi][ni] = __builtin_amdgcn_mfma_f32_16x16x32_bf16(a2[mi], q2, acc[mi][ni], 0, 0, 0);
                acc[mi][ni] = __builtin_amdgcn_mfma_f32_16x16x32_bf16(a3[mi], q1, acc[mi][ni], 0, 0, 0);
            }
        }
    }

    // BN + ReLU, D layout col=lane&15 row=quad*4+r -> h1s
    #pragma unroll
    for (int ni = 0; ni < 4; ni++) {
        int h = n0w + ni * 16 + lq;
        float a = ascS[h], d = dscS[h];
        #pragma unroll
        for (int mi = 0; mi < 2; mi++) {
            #pragma unroll
            for (int r = 0; r < 4; r++) {
                int node = mi * 16 + quad * 4 + r;
                float v = acc[mi][ni][r] * a + d;
                h1s[node][h] = v > 0.f ? v : 0.f;
            }
        }
    }
    __syncthreads();

    // ---- stage 2: h1 @ W2 on VALU (round-3 proven form), K=256 in 4 chunks ----
    int n_loc = t >> 3, cg = t & 7;
    float acc2[5];
    #pragma unroll
    for (int j = 0; j < 5; j++) acc2[j] = b2[cg * 5 + j];

    for (int h0 = 0; h0 < H; h0 += 64) {
        for (int kk = 0; kk < 10; kk++) {
            int idx = kk * 256 + t;         // 2560 elems
            if (idx < 2560) {
                int hh = idx / 40, c = idx % 40;
                w2s[c][hh] = W2[(size_t)(h0 + hh) * C + c];
            }
        }
        __syncthreads();
        #pragma unroll 4
        for (int hh = 0; hh < 64; hh += 4) {
            float4 hv = *((const float4*)&h1s[n_loc][h0 + hh]);
            #pragma unroll
            for (int j = 0; j < 5; j++) {
                float4 w4 = *((const float4*)&w2s[cg * 5 + j][hh]);
                acc2[j] += hv.x * w4.x + hv.y * w4.y + hv.z * w4.z + hv.w * w4.w;
            }
        }
        __syncthreads();
    }

    // epilogue: stash h, sigmoid per node, write h row + out init
    #pragma unroll
    for (int j = 0; j < 5; j++) h1s[n_loc][cg * 5 + j] = acc2[j];
    float part = 0.f;
    #pragma unroll
    for (int j = 0; j < 5; j++) part += acc2[j] * pw[cg * 5 + j];
    redc[t] = part;
    __syncthreads();
    if (cg == 0) {
        float s = 0.f;
        #pragma unroll
        for (int q = 0; q < 8; q++) s += redc[n_loc * 8 + q];
        sigv[n_loc] = 1.f / (1.f + expf(-(s + pb[0])));
    }
    __syncthreads();
    if (t < 160) {                      // 32 rows x 5 packs of 8 floats
        int row = t / 5, p = t % 5;
        int n = n0 + row;
        if (n < N) {
            float4 a, b;
            a.x = h1s[row][8 * p + 0]; a.y = h1s[row][8 * p + 1];
            a.z = h1s[row][8 * p + 2]; a.w = h1s[row][8 * p + 3];
            b.x = h1s[row][8 * p + 4]; b.y = h1s[row][8 * p + 5];
            b.z = h1s[row][8 * p + 6]; b.w = h1s[row][8 * p + 7];
            float4* hp = (float4*)(hbuf + (size_t)n * C + 8 * p);
            hp[0] = a; hp[1] = b;
            float sg = sigv[row];
            float4 oa, ob;
            oa.x = sg * a.x; oa.y = sg * a.y; oa.z = sg * a.z; oa.w = sg * a.w;
            ob.x = sg * b.x; ob.y = sg * b.y; ob.z = sg * b.z; ob.w = sg * b.w;
            float4* op = (float4*)(oacc + (size_t)n * C + 8 * p);
            op[0] = oa; op[1] = ob;
        }
    }
}

// ---------------- one propagation hop, fused with retain-combine ----------------
// 320 threads: 64 nodes/block, 5 lanes/node, 2 float4 per lane.
__global__ void k_hop(const float4* __restrict__ cur4, float4* __restrict__ nxt4,
                      float4* __restrict__ oacc4, const int* __restrict__ rp,
                      const int2* __restrict__ ep,
                      const float* __restrict__ pw, const float* __restrict__ pb, int N) {
    __shared__ float red[320];
    __shared__ float sig[64];
    int t = threadIdx.x;
    int nl = t / 5, p = t % 5;
    int n = blockIdx.x * 64 + nl;
    int c0 = 2 * p;
    float4 a0 = make_float4(0.f, 0.f, 0.f, 0.f);
    float4 a1 = make_float4(0.f, 0.f, 0.f, 0.f);
    if (n < N) {
        int b = rp[n], e = rp[n + 1];
        int j = b;
        for (; j + 4 <= e; j += 4) {
            int2 e0 = ep[j], e1 = ep[j + 1], e2 = ep[j + 2], e3 = ep[j + 3];
            const float4* r0 = cur4 + (size_t)e0.x * 10 + c0;
            const float4* r1 = cur4 + (size_t)e1.x * 10 + c0;
            const float4* r2 = cur4 + (size_t)e2.x * 10 + c0;
            const float4* r3 = cur4 + (size_t)e3.x * 10 + c0;
            float4 v00 = r0[0], v01 = r0[1];
            float4 v10 = r1[0], v11 = r1[1];
            float4 v20 = r2[0], v21 = r2[1];
            float4 v30 = r3[0], v31 = r3[1];
            float w0 = __int_as_float(e0.y), w1 = __int_as_float(e1.y);
            float w2 = __int_as_float(e2.y), w3 = __int_as_float(e3.y);
            a0.x += w0 * v00.x; a0.y += w0 * v00.y; a0.z += w0 * v00.z; a0.w += w0 * v00.w;
            a1.x += w0 * v01.x; a1.y += w0 * v01.y; a1.z += w0 * v01.z; a1.w += w0 * v01.w;
            a0.x += w1 * v10.x; a0.y += w1 * v10.y; a0.z += w1 * v10.z; a0.w += w1 * v10.w;
            a1.x += w1 * v11.x; a1.y += w1 * v11.y; a1.z += w1 * v11.z; a1.w += w1 * v11.w;
            a0.x += w2 * v20.x; a0.y += w2 * v20.y; a0.z += w2 * v20.z; a0.w += w2 * v20.w;
            a1.x += w2 * v21.x; a1.y += w2 * v21.y; a1.z += w2 * v21.z; a1.w += w2 * v21.w;
            a0.x += w3 * v30.x; a0.y += w3 * v30.y; a0.z += w3 * v30.z; a0.w += w3 * v30.w;
            a1.x += w3 * v31.x; a1.y += w3 * v31.y; a1.z += w3 * v31.z; a1.w += w3 * v31.w;
        }
        if (j + 2 <= e) {
            int2 e0 = ep[j], e1 = ep[j + 1];
            const float4* r0 = cur4 + (size_t)e0.x * 10 + c0;
            const float4* r1 = cur4 + (size_t)e1.x * 10 + c0;
            float4 v00 = r0[0], v01 = r0[1];
            float4 v10 = r1[0], v11 = r1[1];
            float w0 = __int_as_float(e0.y), w1 = __int_as_float(e1.y);
            a0.x += w0 * v00.x; a0.y += w0 * v00.y; a0.z += w0 * v00.z; a0.w += w0 * v00.w;
            a1.x += w0 * v01.x; a1.y += w0 * v01.y; a1.z += w0 * v01.z; a1.w += w0 * v01.w;
            a0.x += w1 * v10.x; a0.y += w1 * v10.y; a0.z += w1 * v10.z; a0.w += w1 * v10.w;
            a1.x += w1 * v11.x; a1.y += w1 * v11.y; a1.z += w1 * v11.z; a1.w += w1 * v11.w;
            j += 2;
        }
        if (j < e) {
            int2 e0 = ep[j];
            const float4* r0 = cur4 + (size_t)e0.x * 10 + c0;
            float4 v00 = r0[0], v01 = r0[1];
            float w0 = __int_as_float(e0.y);
            a0.x += w0 * v00.x; a0.y += w0 * v00.y; a0.z += w0 * v00.z; a0.w += w0 * v00.w;
            a1.x += w0 * v01.x; a1.y += w0 * v01.y; a1.z += w0 * v01.z; a1.w += w0 * v01.w;
        }
        nxt4[(size_t)n * 10 + c0] = a0;
        nxt4[(size_t)n * 10 + c0 + 1] = a1;
    }
    // retain-combine
    float4 pw0 = ((const float4*)pw)[c0];
    float4 pw1 = ((const float4*)pw)[c0 + 1];
    red[t] = a0.x * pw0.x + a0.y * pw0.y + a0.z * pw0.z + a0.w * pw0.w
           + a1.x * pw1.x + a1.y * pw1.y + a1.z * pw1.z + a1.w * pw1.w;
    __syncthreads();
    if (p == 0) {
        float s = red[t] + red[t + 1] + red[t + 2] + red[t + 3] + red[t + 4];
        sig[nl] = 1.f / (1.f + expf(-(s + pb[0])));
    }
    __syncthreads();
    if (n < N) {
        float sg = sig[nl];
        size_t o = (size_t)n * 10 + c0;
        float4 v0 = oacc4[o], v1 = oacc4[o + 1];
        v0.x += sg * a0.x; v0.y += sg * a0.y; v0.z += sg * a0.z; v0.w += sg * a0.w;
        v1.x += sg * a1.x; v1.y += sg * a1.y; v1.z += sg * a1.z; v1.w += sg * a1.w;
        oacc4[o] = v0;
        oacc4[o + 1] = v1;
    }
}

// ---------------- in-place log_softmax over C (float4) ----------------
__global__ void k_lsm(float4* __restrict__ io, int N) {
    __shared__ float red[320];
    __shared__ float statm[32];
    __shared__ float stats[32];
    int t = threadIdx.x;
    int nl = t / 10, c4 = t % 10;
    int n = blockIdx.x * 32 + nl;
    bool ok = n < N;
    float4 v = ok ? io[(size_t)n * 10 + c4] : make_float4(-1e30f, -1e30f, -1e30f, -1e30f);
    red[t] = fmaxf(fmaxf(v.x, v.y), fmaxf(v.z, v.w));
    __syncthreads();
    if (c4 == 0) {
        float m = -1e30f;
        #pragma unroll
        for (int q = 0; q < 10; q++) m = fmaxf(m, red[nl * 10 + q]);
        statm[nl] = m;
    }
    __syncthreads();
    float m = statm[nl];
    float e0 = expf(v.x - m), e1 = expf(v.y - m), e2 = expf(v.z - m), e3 = expf(v.w - m);
    red[t] = e0 + e1 + e2 + e3;
    __syncthreads();
    if (c4 == 0) {
        float s = 0.f;
        #pragma unroll
        for (int q = 0; q < 10; q++) s += red[nl * 10 + q];
        stats[nl] = logf(s);
    }
    __syncthreads();
    if (ok) {
        float ls = stats[nl];
        io[(size_t)n * 10 + c4] = make_float4(v.x - m - ls, v.y - m - ls, v.z - m - ls, v.w - m - ls);
    }
}

extern "C" void kernel_launch(void* const* d_in, const int* in_sizes, int n_in,
                              void* d_out, int out_size, void* d_ws, size_t ws_size,
                              hipStream_t stream) {
    const float* x   = (const float*)d_in[0];
    const int*   ei  = (const int*)d_in[1];     // [2,E]: src row then dst row
    const float* nrm = (const float*)d_in[2];
    const float* W1  = (const float*)d_in[3];
    const float* b1  = (const float*)d_in[4];
    const float* g   = (const float*)d_in[5];
    const float* be  = (const float*)d_in[6];
    const float* mu  = (const float*)d_in[7];
    const float* var = (const float*)d_in[8];
    const float* W2  = (const float*)d_in[9];
    const float* b2  = (const float*)d_in[10];
    const float* pw  = (const float*)d_in[11];
    const float* pb  = (const float*)d_in[12];
    float* out = (float*)d_out;

    int N = in_sizes[0] / F;
    int E = in_sizes[2];

    char* w = (char*)d_ws;
    auto alloc = [&](size_t bytes) {
        void* p = (void*)w;
        w += ((bytes + 255) / 256) * 256;
        return p;
    };
    int*    rp     = (int*)alloc((size_t)(N + 1) * 4);
    int*    cursor = (int*)alloc((size_t)(N + 1) * 4);
    int*    bsum   = (int*)alloc(1024);
    int2*   ep     = (int2*)alloc((size_t)E * 8);
    ushort* w1a    = (ushort*)alloc((size_t)F * H * 2);
    ushort* w1b    = (ushort*)alloc((size_t)F * H * 2);
    ushort* w1c    = (ushort*)alloc((size_t)F * H * 2);
    float*  bufA   = (float*)alloc((size_t)N * C * 4);
    float*  bufB   = (float*)alloc((size_t)N * C * 4);

    hipMemsetAsync(cursor, 0, (size_t)(N + 1) * 4, stream);

    k_count<<<(E + 255) / 256, 256, 0, stream>>>(ei + E, E, cursor);

    int n1 = N + 1;
    int NB = (n1 + 4095) / 4096;
    k_scan1<<<NB, 256, 0, stream>>>(cursor, n1, bsum);
    k_scan2<<<1, 64, 0, stream>>>(bsum, NB);
    k_scan3<<<NB, 256, 0, stream>>>(cursor, n1, bsum, rp);

    hipMemsetAsync(cursor, 0, (size_t)(N + 1) * 4, stream);
    k_fill<<<(E + 255) / 256, 256, 0, stream>>>(ei, ei + E, nrm, E, rp, cursor, ep);

    k_wsplit<<<(F * H + 255) / 256, 256, 0, stream>>>(W1, w1a, w1b, w1c);

    k_mlp<<<(N + TM - 1) / TM, 256, 0, stream>>>(x, w1a, w1b, w1c, b1, g, be, mu, var,
                                                 W2, b2, pw, pb, bufA, out, N);

    int nodeBlocks64 = (N + 63) / 64;
    float* cur = bufA;
    float* nxt = bufB;
    for (int k = 0; k < KHOPS; k++) {
        k_hop<<<nodeBlocks64, 320, 0, stream>>>((const float4*)cur, (float4*)nxt, (float4*)out,
                                                rp, ep, pw, pb, N);
        float* tmp = cur; cur = nxt; nxt = tmp;
    }

    int nodeBlocks32 = (N + 31) / 32;
    k_lsm<<<nodeBlocks32, 320, 0, stream>>>((float4*)out, N);
}